// Round 12
// baseline (157.422 us; speedup 1.0000x reference)
//
#include <hip/hip_runtime.h>
#include <hip/hip_bf16.h>
#include <hip/hip_fp8.h>

// ContrastiveLoss (SimCLR InfoNCE): N=8192, D=1024, T=0.1
// nll[i] = -logit[i, (i+N/2)%N] + logsumexp_j(logit[i,j]), diag masked out
// logit = cos_sim / T; out = mean(nll)
//
// Identities:
//  - zn_i = z_i * sqrt(10*log2e)/||z_i||  =>  dot d = logit*log2e and
//    exp(logit-10) = 2^(d - 10*log2e) -> raw v_exp_f32.
//  - logit in [-10,10] => FIXED-offset logsumexp; masked diag term == 0.
//  - Gram symmetric: upper-tri 128x128 supertiles (2080); off-diag tile
//    (I,J) adds exp row-sums to rows of I, col-sums to rows of J.
//  - positive-pair logits = tile diagonals of supertiles (I, I+32).
//  - MX-scaled fp8 K=128 MFMA with all scales = 1.0 (2x bf16 rate).
//
// R24: 4 BLOCKS/CU via 34KB LDS (single-buffer A AND B, both operand frag
// sets hoisted to regs). Evidence: R23 halved DMA bytes at 2 blk/CU ->
// 67.9us (DMA-cap theory REFUTED; staging path/bytes don't matter at fixed
// occupancy). The variable tracking all 12 rounds: hit-regime throughput
// is set by resident blocks -- 3 blk (R17) = 56.4us, every 2-blk variant
// (R18 ping-pong / R23 split-path) = 66-68us regardless of structure, 1-blk
// worse. No pipe >60% (DS~55% incl 2048 conflict-cy/tile, MFMA 20-24%,
// HBM 5%) -> the wall is the per-block phase latency chain (~6.2k cy:
// barrier, lgkm waits, DS burst, MFMA burst), hidden only by block TLP.
// LDS binds occupancy (50KB->3). Cut: sA dbuf->single, keep sB single,
// hoist BOTH A+B frags behind the mid-phase barrier (R12's proven B-hoist,
// extended). Cadence unchanged: entry sync (drains staging) -> 16 frag
// reads -> sync -> stage p+1 into same buffers -> 16 MFMA. Trade: A loses
// dbuf slack (staging covered by MFMA cluster + TLP), buys +1 block.
// ~100 VGPR + 64 AGPR, launch_bounds(256,4) -> no spill risk. Predicted:
// occupancy ~33%, gemm 56.4 -> 44-48us, MfmaUtil 27-31%, WRITE ~19MB.
// Neutral => TLP-scaling refuted -> attack the 2048/tile conflict path.

#define N_ROWS 8192
#define DIM    1024
#define BM 128
#define BK 128                         // bytes (= elems) of K per phase
#define NPHASE (DIM / BK)              // 8
#define NT     (N_ROWS / BM)           // 64
#define NTILES (NT * (NT + 1) / 2)     // 2080
#define OFFS   14.4269504088896340f    // 10 * log2e
#define ROW_SCALE 3.7982825605f        // sqrt(10 * log2e)
#define LN2    0.6931471805599453f
#define LOGIT_MAX 10.0f
#define SCALE1 0x7F7F7F7F              // e8m0 1.0 in every byte

typedef float floatx4 __attribute__((ext_vector_type(4)));
typedef int   intx4   __attribute__((ext_vector_type(4)));
typedef int   intx8   __attribute__((ext_vector_type(8)));

__device__ __forceinline__ void async_copy16(const void* g, void* lds) {
  __builtin_amdgcn_global_load_lds(
      (const __attribute__((address_space(1))) void*)g,
      (__attribute__((address_space(3))) void*)lds, 16, 0, 0);
}

__device__ __forceinline__ unsigned pack4_e4m3(float a, float b, float c, float d) {
  __hip_fp8_e4m3 qa(a), qb(b), qc(c), qd(d);
  return (unsigned)qa.__x | ((unsigned)qb.__x << 8) |
         ((unsigned)qc.__x << 16) | ((unsigned)qd.__x << 24);
}

// ---------------- Kernel 1: row normalize -> fp8 (+ zero accumulators) ----
__global__ __launch_bounds__(256) void normalize_kernel(
    const float* __restrict__ z, unsigned char* __restrict__ zn,
    float* __restrict__ sumexp, float* __restrict__ out) {
  const int tid = threadIdx.x, wave = tid >> 6, lane = tid & 63;
  const int row = blockIdx.x * 4 + wave;

  if (blockIdx.x < 8) ((float4*)sumexp)[blockIdx.x * 256 + tid] = float4{0, 0, 0, 0};
  if (blockIdx.x == 8 && tid == 0) out[0] = 0.0f;

  const float4* zr = (const float4*)(z + (size_t)row * DIM);
  float4 v[4];
  #pragma unroll
  for (int j = 0; j < 4; j++) v[j] = zr[lane + 64 * j];
  float ss = 0.0f;
  #pragma unroll
  for (int j = 0; j < 4; j++)
    ss += v[j].x * v[j].x + v[j].y * v[j].y + v[j].z * v[j].z + v[j].w * v[j].w;
  #pragma unroll
  for (int off = 32; off > 0; off >>= 1) ss += __shfl_xor(ss, off);
  const float scale = rsqrtf(ss) * ROW_SCALE;  // norms ~32 >> eps

  unsigned* o = (unsigned*)(zn + (size_t)row * DIM);
  #pragma unroll
  for (int j = 0; j < 4; j++)
    o[lane + 64 * j] = pack4_e4m3(v[j].x * scale, v[j].y * scale,
                                  v[j].z * scale, v[j].w * scale);
}

// Supercell-major tile decode: 64x64 upper-tri grid partitioned into 8x8
// supercells (rows SI, cols SJ >= SI). Diag cell = 36 tiles, off-diag = 64.
// Prefix P(SI) = 516*SI - 32*SI*SI (P(8)=2080). Within a cell-row: diag
// cell first, then snake over off-diag cells; within cell row-major.
// Confirmed R17: FETCH 66->23MB, gemm 65.3->56.4us.
__device__ __forceinline__ void decode_tile(int g, int& I, int& J) {
  int SI = 0;
  #pragma unroll
  for (int s = 1; s < 8; ++s)
    if (516 * s - 32 * s * s <= g) SI = s;
  int rem = g - (516 * SI - 32 * SI * SI);
  int i, j, SJ;
  if (rem < 36) {                       // diagonal supercell, upper-tri 8x8
    SJ = SI;
    i = 0;
    while ((i + 1) * (17 - (i + 1)) / 2 <= rem) ++i;  // prefix(i)=i*(17-i)/2
    j = i + (rem - i * (17 - i) / 2);
  } else {                              // full off-diagonal supercell
    const int rem2 = rem - 36;
    const int cc = rem2 >> 6;           // 0 .. (6-SI)
    const int k  = rem2 & 63;
    SJ = (SI & 1) ? (7 - cc) : (SI + 1 + cc);
    i = k >> 3;
    j = k & 7;
  }
  I = SI * 8 + i;
  J = SJ * 8 + j;
}

// ---------------- Kernel 2: upper-tri MX-fp8 GEMM + partial sum-exp -------
__global__ __launch_bounds__(256, 4) void fused_gemm_lse(
    const unsigned char* __restrict__ zn, float* __restrict__ sumexp,
    float* __restrict__ pos) {
  __shared__ unsigned char sA[BM * BK];       // 16 KB (single buffer)
  __shared__ unsigned char sB[BM * BK];       // 16 KB (single buffer)
  __shared__ float rowRed[2][BM];             // 1 KB
  __shared__ float colRed[2][BM];             // 1 KB   (total 34 KB -> 4 blk/CU)

  const int tid  = threadIdx.x;
  const int lane = tid & 63;
  const int wave = tid >> 6;
  const int quad = lane >> 4;
  const int l15  = lane & 15;
  const int waveM = wave >> 1;  // 0..1
  const int waveN = wave & 1;   // 0..1

  // XCD-contiguous tile permutation (2080 = 8 * 260)
  const int t = (blockIdx.x & 7) * (NTILES / 8) + (blockIdx.x >> 3);
  int I, J;
  decode_tile(t, I, J);
  const int rowBase = I * BM, colBase = J * BM;

  // staging: 128x128B tile = 1024 16B-chunks, 4/thread/matrix.
  // chunk s: row r = s>>3, stored slot s&7 holds logical 16B k-chunk
  // q = (s&7) ^ (r&7)  (XOR swizzle, applied on the global-address side).
  const unsigned char* aP[4];
  const unsigned char* bP[4];
  int soff[4];
  #pragma unroll
  for (int i = 0; i < 4; i++) {
    const int s = i * 256 + tid;            // i*256 + wave*64 + lane
    const int r = s >> 3;                   // tile row 0..127
    const int q = (s & 7) ^ (r & 7);        // logical k-chunk 0..7
    aP[i] = zn + (size_t)(rowBase + r) * DIM + q * 16;
    bP[i] = zn + (size_t)(colBase + r) * DIM + q * 16;
    soff[i] = s * 16;                       // wave-uniform base + lane*16
  }
  auto stageAB = [&]() {                    // next phase into the single bufs
    #pragma unroll
    for (int i = 0; i < 4; i++) {
      async_copy16(aP[i], (char*)sA + soff[i]);
      aP[i] += BK;
    }
    #pragma unroll
    for (int i = 0; i < 4; i++) {
      async_copy16(bP[i], (char*)sB + soff[i]);
      bP[i] += BK;
    }
  };

  floatx4 acc[4][4];
  #pragma unroll
  for (int mi = 0; mi < 4; mi++)
    #pragma unroll
    for (int ni = 0; ni < 4; ni++) acc[mi][ni] = {0.f, 0.f, 0.f, 0.f};

  stageAB();                             // phase 0 (only cold fill)

  for (int p = 0; p < NPHASE; ++p) {
    __syncthreads();                 // staging of phase p complete (vmcnt)

    // hoist BOTH operand fragment sets to registers (bufs re-staged below)
    intx8 aa[4], bb[4];
    #pragma unroll
    for (int ni = 0; ni < 4; ni++) {
      const int r = waveN * 64 + ni * 16 + l15;
      const int c0 = (quad * 2) ^ (r & 7);
      const intx4 lo = *(const intx4*)(&sB[0] + (r * 8 + c0) * 16);
      const intx4 hi = *(const intx4*)(&sB[0] + (r * 8 + (c0 ^ 1)) * 16);
      bb[ni] = __builtin_shufflevector(lo, hi, 0, 1, 2, 3, 4, 5, 6, 7);
    }
    #pragma unroll
    for (int mi = 0; mi < 4; mi++) {
      const int r = waveM * 64 + mi * 16 + l15;
      const int c0 = (quad * 2) ^ (r & 7);
      const intx4 lo = *(const intx4*)(&sA[0] + (r * 8 + c0) * 16);
      const intx4 hi = *(const intx4*)(&sA[0] + (r * 8 + (c0 ^ 1)) * 16);
      aa[mi] = __builtin_shufflevector(lo, hi, 0, 1, 2, 3, 4, 5, 6, 7);
    }
    __syncthreads();                 // all waves done reading sA/sB (lgkm)

    if (p + 1 < NPHASE) stageAB();   // async prefetch into the same buffers

    #pragma unroll
    for (int mi = 0; mi < 4; mi++)
      #pragma unroll
      for (int ni = 0; ni < 4; ni++)
        acc[mi][ni] = __builtin_amdgcn_mfma_scale_f32_16x16x128_f8f6f4(
            aa[mi], bb[ni], acc[mi][ni],
            0 /*cbsz: A=e4m3*/, 0 /*blgp: B=e4m3*/,
            0, SCALE1,   // opsel_a, scale_a = 1.0
            0, SCALE1);  // opsel_b, scale_b = 1.0
  }

  // ---- epilogue ----
  // C/D layout (16x16 shape family): col = lane&15, row = quad*4 + reg
  const bool diagBlk = (I == J);

  if (J == I + 32 && waveM == waveN) {  // positive-pair supertile
    #pragma unroll
    for (int mi = 0; mi < 4; mi++)
      #pragma unroll
      for (int r = 0; r < 4; r++)
        if (l15 == quad * 4 + r)
          pos[rowBase + waveM * 64 + mi * 16 + l15] = acc[mi][mi][r];
  }

  float rsum[4][4], csum[4];
  #pragma unroll
  for (int mi = 0; mi < 4; mi++)
    #pragma unroll
    for (int r = 0; r < 4; r++) rsum[mi][r] = 0.0f;
  #pragma unroll
  for (int ni = 0; ni < 4; ni++) csum[ni] = 0.0f;

  if (diagBlk) {
    #pragma unroll
    for (int mi = 0; mi < 4; mi++)
      #pragma unroll
      for (int ni = 0; ni < 4; ni++) {
        const bool dtile = (waveM == waveN) && (mi == ni);
        #pragma unroll
        for (int r = 0; r < 4; r++) {
          float e = exp2f(acc[mi][ni][r] - OFFS);
          if (dtile && l15 == quad * 4 + r) e = 0.0f;  // masked diagonal
          rsum[mi][r] += e;
        }
      }
  } else {
    #pragma unroll
    for (int mi = 0; mi < 4; mi++)
      #pragma unroll
      for (int ni = 0; ni < 4; ni++)
        #pragma unroll
        for (int r = 0; r < 4; r++) {
          const float e = exp2f(acc[mi][ni][r] - OFFS);
          rsum[mi][r] += e;
          csum[ni]    += e;
        }
  }

  #pragma unroll
  for (int mi = 0; mi < 4; mi++)
    #pragma unroll
    for (int r = 0; r < 4; r++) {
      float v = rsum[mi][r];
      v += __shfl_xor(v, 1);
      v += __shfl_xor(v, 2);
      v += __shfl_xor(v, 4);
      v += __shfl_xor(v, 8);
      if (l15 == 0)
        rowRed[waveN][waveM * 64 + mi * 16 + quad * 4 + r] = v;
    }
  if (!diagBlk) {
    #pragma unroll
    for (int ni = 0; ni < 4; ni++) {
      float v = csum[ni];
      v += __shfl_xor(v, 16);
      v += __shfl_xor(v, 32);
      if (quad == 0)
        colRed[waveM][waveN * 64 + ni * 16 + l15] = v;
    }
  }
  __syncthreads();

  if (tid < BM) {
    atomicAdd(&sumexp[rowBase + tid], rowRed[0][tid] + rowRed[1][tid]);
  } else if (!diagBlk) {
    const int c = tid - BM;
    atomicAdd(&sumexp[colBase + c], colRed[0][c] + colRed[1][c]);
  }
}

// ---------------- Kernel 3: mean NLL --------------------------------------
__global__ __launch_bounds__(256) void finalize_kernel(
    const float* __restrict__ sumexp, const float* __restrict__ pos,
    float* __restrict__ out) {
  const int tid = threadIdx.x;
  const int row = blockIdx.x * 256 + tid;
  // pos holds d = logit*log2e for rows [0,4096); pos[i+4096] == pos[i]
  float local = -(pos[row & (N_ROWS / 2 - 1)] * LN2) + LOGIT_MAX + logf(sumexp[row]);
  #pragma unroll
  for (int off = 32; off > 0; off >>= 1) local += __shfl_xor(local, off);
  __shared__ float red[4];
  const int wave = tid >> 6, lane = tid & 63;
  if (lane == 0) red[wave] = local;
  __syncthreads();
  if (tid == 0)
    atomicAdd(out, (red[0] + red[1] + red[2] + red[3]) * (1.0f / N_ROWS));
}

extern "C" void kernel_launch(void* const* d_in, const int* in_sizes, int n_in,
                              void* d_out, int out_size, void* d_ws, size_t ws_size,
                              hipStream_t stream) {
  const float* z = (const float*)d_in[0];
  float* out = (float*)d_out;

  char* ws = (char*)d_ws;
  unsigned char* zn = (unsigned char*)ws;                    // 8 MB fp8
  float* sumexp = (float*)(ws + (size_t)N_ROWS * DIM);       // 32 KB
  float* pos    = sumexp + N_ROWS;                           // 16 KB

  normalize_kernel<<<N_ROWS / 4, 256, 0, stream>>>(z, zn, sumexp, out);
  fused_gemm_lse<<<NTILES, 256, 0, stream>>>(zn, sumexp, pos);
  finalize_kernel<<<N_ROWS / 256, 256, 0, stream>>>(sumexp, pos, out);
}

// Round 13
// 121.354 us; speedup vs baseline: 1.2972x; 1.2972x over previous
//
#include <hip/hip_runtime.h>
#include <hip/hip_bf16.h>
#include <hip/hip_fp8.h>

// ContrastiveLoss (SimCLR InfoNCE): N=8192, D=1024, T=0.1
// nll[i] = -logit[i, (i+N/2)%N] + logsumexp_j(logit[i,j]), diag masked out
// logit = cos_sim / T; out = mean(nll)
//
// Identities:
//  - zn_i = z_i * sqrt(10*log2e)/||z_i||  =>  dot d = logit*log2e and
//    exp(logit-10) = 2^(d - 10*log2e) -> raw v_exp_f32.
//  - logit in [-10,10] => FIXED-offset logsumexp; masked diag term == 0.
//  - Gram symmetric: upper-tri 128x128 supertiles (2080); off-diag tile
//    (I,J) adds exp row-sums to rows of I, col-sums to rows of J.
//  - positive-pair logits = tile diagonals of supertiles (I, I+32).
//  - MX-scaled fp8 K=128 MFMA with all scales = 1.0 (2x bf16 rate).
//
// R25: counted-vmcnt at 3 blocks/CU -- the untested cell. R24 proved 4
// blk/CU is register-impossible (budget 128 < acc 64 + frags 64 + addr;
// VGPR=64, WRITE 161MB spill). Ledger: R17 (3 blk, vmcnt(0)) = 56.4us is
// best; ALL counted-vmcnt/pipeline tests (R13/14/15/18/23) ran at 2 blk or
// miss regime -- rule #23: their nulls don't transfer. R17's entry barrier
// still drains vmcnt(0) with only ~400cy MFMA slack vs ~600cy L2 latency.
// Restructure: hoist BOTH frag sets before barrier2 (it then covers all
// reads of sA[b] and sB) -> stage B(p+1) + A(p+2) (A two-deep; its dest is
// the buffer just fully read) -> MFMA. Entry wait = vmcnt(4): newest 4 =
// A(p+2) stay in flight; B(p)/A(p) issued a FULL PHASE ago -> wait ~free.
// Only p=7 drains to 0. Regs: 52 non-frag + aa 32 + bb 32 + acc 64 = ~164
// <= 170 at (256,3); ptr arrays collapsed to gA/gB + rOff[4] to shave 12.
// SPILL TRIPWIRE: WRITE_SIZE ~19MB, VGPR ~100-110; WRITE>30MB = discard.
// Predicted: gemm 56.4 -> 46-50us, MfmaUtil 27-30%. Clean+neutral =>
// drain never bound at 3 blk; structure within ~10% of latency floor.

#define N_ROWS 8192
#define DIM    1024
#define BM 128
#define BK 128                         // bytes (= elems) of K per phase
#define NPHASE (DIM / BK)              // 8
#define NT     (N_ROWS / BM)           // 64
#define NTILES (NT * (NT + 1) / 2)     // 2080
#define OFFS   14.4269504088896340f    // 10 * log2e
#define ROW_SCALE 3.7982825605f        // sqrt(10 * log2e)
#define LN2    0.6931471805599453f
#define LOGIT_MAX 10.0f
#define SCALE1 0x7F7F7F7F              // e8m0 1.0 in every byte

typedef float floatx4 __attribute__((ext_vector_type(4)));
typedef int   intx4   __attribute__((ext_vector_type(4)));
typedef int   intx8   __attribute__((ext_vector_type(8)));

__device__ __forceinline__ void async_copy16(const void* g, void* lds) {
  __builtin_amdgcn_global_load_lds(
      (const __attribute__((address_space(1))) void*)g,
      (__attribute__((address_space(3))) void*)lds, 16, 0, 0);
}

__device__ __forceinline__ unsigned pack4_e4m3(float a, float b, float c, float d) {
  __hip_fp8_e4m3 qa(a), qb(b), qc(c), qd(d);
  return (unsigned)qa.__x | ((unsigned)qb.__x << 8) |
         ((unsigned)qc.__x << 16) | ((unsigned)qd.__x << 24);
}

// ---------------- Kernel 1: row normalize -> fp8 (+ zero accumulators) ----
__global__ __launch_bounds__(256) void normalize_kernel(
    const float* __restrict__ z, unsigned char* __restrict__ zn,
    float* __restrict__ sumexp, float* __restrict__ out) {
  const int tid = threadIdx.x, wave = tid >> 6, lane = tid & 63;
  const int row = blockIdx.x * 4 + wave;

  if (blockIdx.x < 8) ((float4*)sumexp)[blockIdx.x * 256 + tid] = float4{0, 0, 0, 0};
  if (blockIdx.x == 8 && tid == 0) out[0] = 0.0f;

  const float4* zr = (const float4*)(z + (size_t)row * DIM);
  float4 v[4];
  #pragma unroll
  for (int j = 0; j < 4; j++) v[j] = zr[lane + 64 * j];
  float ss = 0.0f;
  #pragma unroll
  for (int j = 0; j < 4; j++)
    ss += v[j].x * v[j].x + v[j].y * v[j].y + v[j].z * v[j].z + v[j].w * v[j].w;
  #pragma unroll
  for (int off = 32; off > 0; off >>= 1) ss += __shfl_xor(ss, off);
  const float scale = rsqrtf(ss) * ROW_SCALE;  // norms ~32 >> eps

  unsigned* o = (unsigned*)(zn + (size_t)row * DIM);
  #pragma unroll
  for (int j = 0; j < 4; j++)
    o[lane + 64 * j] = pack4_e4m3(v[j].x * scale, v[j].y * scale,
                                  v[j].z * scale, v[j].w * scale);
}

// Supercell-major tile decode: 64x64 upper-tri grid partitioned into 8x8
// supercells (rows SI, cols SJ >= SI). Diag cell = 36 tiles, off-diag = 64.
// Prefix P(SI) = 516*SI - 32*SI*SI (P(8)=2080). Within a cell-row: diag
// cell first, then snake over off-diag cells; within cell row-major.
// Confirmed R17: FETCH 66->23MB, gemm 65.3->56.4us.
__device__ __forceinline__ void decode_tile(int g, int& I, int& J) {
  int SI = 0;
  #pragma unroll
  for (int s = 1; s < 8; ++s)
    if (516 * s - 32 * s * s <= g) SI = s;
  int rem = g - (516 * SI - 32 * SI * SI);
  int i, j, SJ;
  if (rem < 36) {                       // diagonal supercell, upper-tri 8x8
    SJ = SI;
    i = 0;
    while ((i + 1) * (17 - (i + 1)) / 2 <= rem) ++i;  // prefix(i)=i*(17-i)/2
    j = i + (rem - i * (17 - i) / 2);
  } else {                              // full off-diagonal supercell
    const int rem2 = rem - 36;
    const int cc = rem2 >> 6;           // 0 .. (6-SI)
    const int k  = rem2 & 63;
    SJ = (SI & 1) ? (7 - cc) : (SI + 1 + cc);
    i = k >> 3;
    j = k & 7;
  }
  I = SI * 8 + i;
  J = SJ * 8 + j;
}

// ---------------- Kernel 2: upper-tri MX-fp8 GEMM + partial sum-exp -------
__global__ __launch_bounds__(256, 3) void fused_gemm_lse(
    const unsigned char* __restrict__ zn, float* __restrict__ sumexp,
    float* __restrict__ pos) {
  __shared__ unsigned char sA[2][BM * BK];    // 2 x 16 KB (2-deep DMA dbuf)
  __shared__ unsigned char sB[BM * BK];       // 16 KB (single, 1-deep)
  __shared__ float rowRed[2][BM];             // 1 KB
  __shared__ float colRed[2][BM];             // 1 KB   (total 50 KB)

  const int tid  = threadIdx.x;
  const int lane = tid & 63;
  const int wave = tid >> 6;
  const int quad = lane >> 4;
  const int l15  = lane & 15;
  const int waveM = wave >> 1;  // 0..1
  const int waveN = wave & 1;   // 0..1

  // XCD-contiguous tile permutation (2080 = 8 * 260)
  const int t = (blockIdx.x & 7) * (NTILES / 8) + (blockIdx.x >> 3);
  int I, J;
  decode_tile(t, I, J);
  const int rowBase = I * BM, colBase = J * BM;

  // staging: 128x128B tile = 1024 16B-chunks, 4/thread/matrix.
  // chunk s = i*256+tid: row r = s>>3, stored slot s&7 holds logical
  // k-chunk q = (s&7)^(r&7) (XOR swizzle on the global-address side).
  // LDS dest is linear: s*16 = i*4096 + tid*16.
  int rOff[4];
  #pragma unroll
  for (int i = 0; i < 4; i++) {
    const int s = i * 256 + tid;
    const int r = s >> 3;
    const int q = (s & 7) ^ (r & 7);
    rOff[i] = r * DIM + q * 16;
  }
  const unsigned char* gA = zn + (size_t)rowBase * DIM;
  const unsigned char* gB = zn + (size_t)colBase * DIM;
  const int ldsOff = tid * 16;

  auto stageA = [&](int buf, int p) {
    const unsigned char* g = gA + p * BK;
    #pragma unroll
    for (int i = 0; i < 4; i++)
      async_copy16(g + rOff[i], (char*)sA[buf] + i * 4096 + ldsOff);
  };
  auto stageB = [&](int p) {
    const unsigned char* g = gB + p * BK;
    #pragma unroll
    for (int i = 0; i < 4; i++)
      async_copy16(g + rOff[i], (char*)sB + i * 4096 + ldsOff);
  };

  floatx4 acc[4][4];
  #pragma unroll
  for (int mi = 0; mi < 4; mi++)
    #pragma unroll
    for (int ni = 0; ni < 4; ni++) acc[mi][ni] = {0.f, 0.f, 0.f, 0.f};

  // prologue: B(0), A(0), A(1) in flight (12 insts); entry p=0 waits
  // vmcnt(4) -> drains B(0),A(0), leaves A(1) flying (steady invariant).
  stageB(0);
  stageA(0, 0);
  stageA(1, 1);

  for (int p = 0; p < NPHASE; ++p) {
    const int b = p & 1;
    // entry: B(p),A(p) resident (issued >= 1 full phase ago -> wait ~free);
    // newest 4 outstanding = A(p+2)'s predecessor set; only p=7 drains all.
    if (p < NPHASE - 1) asm volatile("s_waitcnt vmcnt(4)" ::: "memory");
    else                asm volatile("s_waitcnt vmcnt(0)" ::: "memory");
    __builtin_amdgcn_s_barrier();

    // hoist BOTH operand fragment sets (barrier2 then covers all reads)
    intx8 aa[4], bb[4];
    #pragma unroll
    for (int ni = 0; ni < 4; ni++) {
      const int r = waveN * 64 + ni * 16 + l15;
      const int c0 = (quad * 2) ^ (r & 7);
      const intx4 lo = *(const intx4*)(&sB[0] + (r * 8 + c0) * 16);
      const intx4 hi = *(const intx4*)(&sB[0] + (r * 8 + (c0 ^ 1)) * 16);
      bb[ni] = __builtin_shufflevector(lo, hi, 0, 1, 2, 3, 4, 5, 6, 7);
    }
    #pragma unroll
    for (int mi = 0; mi < 4; mi++) {
      const int r = waveM * 64 + mi * 16 + l15;
      const int c0 = (quad * 2) ^ (r & 7);
      const intx4 lo = *(const intx4*)(&sA[b][0] + (r * 8 + c0) * 16);
      const intx4 hi = *(const intx4*)(&sA[b][0] + (r * 8 + (c0 ^ 1)) * 16);
      aa[mi] = __builtin_shufflevector(lo, hi, 0, 1, 2, 3, 4, 5, 6, 7);
    }
    asm volatile("s_waitcnt lgkmcnt(0)" ::: "memory");
    __builtin_amdgcn_sched_barrier(0);
    __builtin_amdgcn_s_barrier();        // all waves done with sB and sA[b]

    // stage: B(p+1) -> sB (freed), A(p+2) -> sA[b] (freed). Issue order
    // B-then-A keeps the entry vmcnt(4) invariant (newest 4 = A batch).
    if (p + 1 < NPHASE) stageB(p + 1);
    if (p + 2 < NPHASE) stageA(b, p + 2);

    __builtin_amdgcn_s_setprio(1);
    #pragma unroll
    for (int mi = 0; mi < 4; mi++)
      #pragma unroll
      for (int ni = 0; ni < 4; ni++)
        acc[mi][ni] = __builtin_amdgcn_mfma_scale_f32_16x16x128_f8f6f4(
            aa[mi], bb[ni], acc[mi][ni],
            0 /*cbsz: A=e4m3*/, 0 /*blgp: B=e4m3*/,
            0, SCALE1,   // opsel_a, scale_a = 1.0
            0, SCALE1);  // opsel_b, scale_b = 1.0
    __builtin_amdgcn_s_setprio(0);
  }

  // ---- epilogue ----
  // C/D layout (16x16 shape family): col = lane&15, row = quad*4 + reg
  const bool diagBlk = (I == J);

  if (J == I + 32 && waveM == waveN) {  // positive-pair supertile
    #pragma unroll
    for (int mi = 0; mi < 4; mi++)
      #pragma unroll
      for (int r = 0; r < 4; r++)
        if (l15 == quad * 4 + r)
          pos[rowBase + waveM * 64 + mi * 16 + l15] = acc[mi][mi][r];
  }

  float rsum[4][4], csum[4];
  #pragma unroll
  for (int mi = 0; mi < 4; mi++)
    #pragma unroll
    for (int r = 0; r < 4; r++) rsum[mi][r] = 0.0f;
  #pragma unroll
  for (int ni = 0; ni < 4; ni++) csum[ni] = 0.0f;

  if (diagBlk) {
    #pragma unroll
    for (int mi = 0; mi < 4; mi++)
      #pragma unroll
      for (int ni = 0; ni < 4; ni++) {
        const bool dtile = (waveM == waveN) && (mi == ni);
        #pragma unroll
        for (int r = 0; r < 4; r++) {
          float e = exp2f(acc[mi][ni][r] - OFFS);
          if (dtile && l15 == quad * 4 + r) e = 0.0f;  // masked diagonal
          rsum[mi][r] += e;
        }
      }
  } else {
    #pragma unroll
    for (int mi = 0; mi < 4; mi++)
      #pragma unroll
      for (int ni = 0; ni < 4; ni++)
        #pragma unroll
        for (int r = 0; r < 4; r++) {
          const float e = exp2f(acc[mi][ni][r] - OFFS);
          rsum[mi][r] += e;
          csum[ni]    += e;
        }
  }

  #pragma unroll
  for (int mi = 0; mi < 4; mi++)
    #pragma unroll
    for (int r = 0; r < 4; r++) {
      float v = rsum[mi][r];
      v += __shfl_xor(v, 1);
      v += __shfl_xor(v, 2);
      v += __shfl_xor(v, 4);
      v += __shfl_xor(v, 8);
      if (l15 == 0)
        rowRed[waveN][waveM * 64 + mi * 16 + quad * 4 + r] = v;
    }
  if (!diagBlk) {
    #pragma unroll
    for (int ni = 0; ni < 4; ni++) {
      float v = csum[ni];
      v += __shfl_xor(v, 16);
      v += __shfl_xor(v, 32);
      if (quad == 0)
        colRed[waveM][waveN * 64 + ni * 16 + l15] = v;
    }
  }
  __syncthreads();

  if (tid < BM) {
    atomicAdd(&sumexp[rowBase + tid], rowRed[0][tid] + rowRed[1][tid]);
  } else if (!diagBlk) {
    const int c = tid - BM;
    atomicAdd(&sumexp[colBase + c], colRed[0][c] + colRed[1][c]);
  }
}

// ---------------- Kernel 3: mean NLL --------------------------------------
__global__ __launch_bounds__(256) void finalize_kernel(
    const float* __restrict__ sumexp, const float* __restrict__ pos,
    float* __restrict__ out) {
  const int tid = threadIdx.x;
  const int row = blockIdx.x * 256 + tid;
  // pos holds d = logit*log2e for rows [0,4096); pos[i+4096] == pos[i]
  float local = -(pos[row & (N_ROWS / 2 - 1)] * LN2) + LOGIT_MAX + logf(sumexp[row]);
  #pragma unroll
  for (int off = 32; off > 0; off >>= 1) local += __shfl_xor(local, off);
  __shared__ float red[4];
  const int wave = tid >> 6, lane = tid & 63;
  if (lane == 0) red[wave] = local;
  __syncthreads();
  if (tid == 0)
    atomicAdd(out, (red[0] + red[1] + red[2] + red[3]) * (1.0f / N_ROWS));
}

extern "C" void kernel_launch(void* const* d_in, const int* in_sizes, int n_in,
                              void* d_out, int out_size, void* d_ws, size_t ws_size,
                              hipStream_t stream) {
  const float* z = (const float*)d_in[0];
  float* out = (float*)d_out;

  char* ws = (char*)d_ws;
  unsigned char* zn = (unsigned char*)ws;                    // 8 MB fp8
  float* sumexp = (float*)(ws + (size_t)N_ROWS * DIM);       // 32 KB
  float* pos    = sumexp + N_ROWS;                           // 16 KB

  normalize_kernel<<<N_ROWS / 4, 256, 0, stream>>>(z, zn, sumexp, out);
  fused_gemm_lse<<<NTILES, 256, 0, stream>>>(zn, sumexp, pos);
  finalize_kernel<<<N_ROWS / 256, 256, 0, stream>>>(sumexp, pos, out);
}